// Round 15
// baseline (386.726 us; speedup 1.0000x reference)
//
#include <hip/hip_runtime.h>

typedef unsigned short u16;
typedef __attribute__((ext_vector_type(8))) short bf16x8;
typedef __attribute__((ext_vector_type(4))) float f32x4;

__device__ __forceinline__ float bf2f(u16 u){
  union { unsigned int i; float f; } x; x.i = ((unsigned int)u) << 16; return x.f;
}
__device__ __forceinline__ u16 f2bf(float f){
  union { float f; unsigned int i; } x; x.f = f;
  unsigned int r = x.i + 0x7fffu + ((x.i >> 16) & 1u);
  return (u16)(r >> 16);
}

template<int N> __device__ __forceinline__ void waitcnt_vm(){
  if constexpr (N==0)       asm volatile("s_waitcnt vmcnt(0)" ::: "memory");
  else if constexpr (N==2)  asm volatile("s_waitcnt vmcnt(2)" ::: "memory");
  else if constexpr (N==3)  asm volatile("s_waitcnt vmcnt(3)" ::: "memory");
  else if constexpr (N==4)  asm volatile("s_waitcnt vmcnt(4)" ::: "memory");
  else if constexpr (N==6)  asm volatile("s_waitcnt vmcnt(6)" ::: "memory");
  else if constexpr (N==8)  asm volatile("s_waitcnt vmcnt(8)" ::: "memory");
  else if constexpr (N==12) asm volatile("s_waitcnt vmcnt(12)" ::: "memory");
}

// ---------------- merged prep: 4x f32->bf16 cvt + conv weight transpose -----
__device__ __forceinline__ void cvt4(const float* __restrict__ in,
                                     u16* __restrict__ out, int blk){
  int i = blk*256 + threadIdx.x;
  float4 v = reinterpret_cast<const float4*>(in)[i];
  reinterpret_cast<ushort4*>(out)[i] =
      make_ushort4(f2bf(v.x), f2bf(v.y), f2bf(v.z), f2bf(v.w));
}
__global__ __launch_bounds__(256) void prep_all(
    const float* __restrict__ u, const float* __restrict__ w_in,
    const float* __restrict__ w_out, const float* __restrict__ D_w,
    const float* __restrict__ conv_w,
    u16* __restrict__ ub, u16* __restrict__ w1b, u16* __restrict__ w2b,
    u16* __restrict__ dwb, u16* __restrict__ wtb)
{
  const int b = blockIdx.x;
  if      (b < 8192)  cvt4(u,     ub,  b);
  else if (b < 12608) cvt4(w_in,  w1b, b-8192);
  else if (b < 14656) cvt4(w_out, w2b, b-12608);
  else if (b < 14720) cvt4(D_w,   dwb, b-14656);
  else {
    int i = (b-14720)*256 + threadIdx.x;
    if (i < 2304*7){
      int ch = i / 7, t = i % 7;
      wtb[t*2304 + ch] = f2bf(conv_w[i]);
    }
  }
}

// ====== counted-vmcnt pipelined bf16 MFMA GEMM, BK=32, 3 LDS bufs ===========
// SAFE ordering (r8-proven): waitcnt vmcnt(LPS) -> s_barrier -> stage(t+2)
// -> comp(t). Tile ladder measured (r8/r9/r12): 72KB/2-CU=135us,
// 48KB(128x128)/3-CU=110us OPTIMUM, 36KB(128x64)/4-CU=135us. m-fastest XCD
// mapping keeps B-tile hot in per-XCD L2 (r10: FETCH 116->60MB).
// gridDim.y%8==0 required. MODE 0: f32 out. MODE 2: split z/xbc/dt (gemm1).
template<int GUARD, int MODE, int BM, int BN, int NM, int NN>
__global__ __launch_bounds__(256, 3) void gemm_p(
    const u16* __restrict__ A, int lda,
    const u16* __restrict__ Bt, int ldb,
    void* __restrict__ Cp, int ldc,
    int M, int N, int K,
    u16* __restrict__ zb, u16* __restrict__ xb, u16* __restrict__ db_)
{
  constexpr int T   = 64*NM*NN;
  constexpr int MF  = BM/NM/16;
  constexpr int NF  = BN/NN/16;
  constexpr int LPS = (BM+BN)*4/T;       // gload_lds per thread per stage
  __shared__ __align__(16) u16 As[3][BM*32];
  __shared__ __align__(16) u16 Bs[3][BN*32];
  const int tid  = threadIdx.x;
  const int wid  = tid >> 6;
  const int lane = tid & 63;
  // XCD-chunked bijective mapping, m-fastest within XCD (L2 B-tile reuse)
  const int bid   = blockIdx.y * gridDim.x + blockIdx.x;
  const int xcd   = bid & 7;
  const int local = bid >> 3;
  const int mPerX = gridDim.y >> 3;      // m-tiles owned by one XCD
  const int m0 = (xcd*mPerX + (local % mPerX)) * BM;
  const int n0 = (local / mPerX) * BN;
  const int wm = wid / NN;
  const int wn = wid % NN;
  const int lq = lane >> 4, lr = lane & 15;
  // read-side XOR (must match stage()'s source-column XOR)
  const int ce = (lq ^ ((lr&3) ^ ((lr>>2)&3))) * 8;

  f32x4 acc[MF][NF];
  #pragma unroll
  for (int m=0;m<MF;m++)
    #pragma unroll
    for (int n=0;n<NF;n++) acc[m][n] = (f32x4){0.f,0.f,0.f,0.f};

  auto stage = [&](int t){
    const int buf = t % 3;
    const int k0  = t << 5;
    #pragma unroll
    for (int i=0;i<(BM*4)/T;i++){
      int slot = i*T + tid;
      int row = slot >> 2, cg = slot & 3;
      int sc = cg ^ ((row&3) ^ ((row>>2)&3));
      const u16* ga = A + (size_t)(m0 + row)*lda + k0 + sc*8;
      __builtin_amdgcn_global_load_lds(
        (const __attribute__((address_space(1))) void*)ga,
        (__attribute__((address_space(3))) void*)&As[buf][slot*8], 16, 0, 0);
    }
    #pragma unroll
    for (int i=0;i<(BN*4)/T;i++){
      int slot = i*T + tid;
      int row = slot >> 2, cg = slot & 3;
      int gn = n0 + row;
      if (GUARD) gn = (gn < N) ? gn : (N-1);
      int sc = cg ^ ((row&3) ^ ((row>>2)&3));
      const u16* gb = Bt + (size_t)gn*ldb + k0 + sc*8;
      __builtin_amdgcn_global_load_lds(
        (const __attribute__((address_space(1))) void*)gb,
        (__attribute__((address_space(3))) void*)&Bs[buf][slot*8], 16, 0, 0);
    }
  };

  auto comp = [&](int t){
    const int buf = t % 3;
    bf16x8 af[MF], bfr[NF];
    #pragma unroll
    for (int m=0;m<MF;m++){
      int row = wm*(MF*16) + m*16 + lr;
      af[m] = *reinterpret_cast<const bf16x8*>(&As[buf][row*32 + ce]);
    }
    #pragma unroll
    for (int n=0;n<NF;n++){
      int row = wn*(NF*16) + n*16 + lr;
      bfr[n] = *reinterpret_cast<const bf16x8*>(&Bs[buf][row*32 + ce]);
    }
    __builtin_amdgcn_s_setprio(1);
    #pragma unroll
    for (int m=0;m<MF;m++)
      #pragma unroll
      for (int n=0;n<NF;n++)
        acc[m][n] = __builtin_amdgcn_mfma_f32_16x16x32_bf16(af[m], bfr[n], acc[m][n], 0,0,0);
    __builtin_amdgcn_s_setprio(0);
  };

  const int nt = K >> 5;                 // >= 4 for all our shapes
  stage(0); stage(1);
  for (int t=0; t<nt; ++t){
    if (t+1 < nt) waitcnt_vm<LPS>();
    else          waitcnt_vm<0>();
    asm volatile("s_barrier" ::: "memory");
    if (t+2 < nt) stage(t+2);
    comp(t);
  }

  #pragma unroll
  for (int m=0;m<MF;m++){
    int row = m0 + wm*(MF*16) + m*16 + lq*4;
    #pragma unroll
    for (int n=0;n<NF;n++){
      int col = n0 + wn*(NF*16) + n*16 + lr;
      if (!GUARD || col < N){
        #pragma unroll
        for (int j=0;j<4;j++){
          float v = acc[m][n][j];
          size_t r = (size_t)(row+j);
          if (MODE == 0)      ((float*)Cp)[r*ldc + col] = v;
          else if (MODE == 1) ((u16*)Cp)[r*ldc + col] = f2bf(v);
          else {
            u16 bv = f2bf(v);
            if (col < 2048)      zb[r*2048 + col] = bv;
            else if (col < 4352) xb[r*2304 + (col-2048)] = bv;
            else                 db_[r*64 + (col-4352)] = bv;
          }
        }
      }
    }
  }
}

// ---------------- depthwise conv7 (SAME) + bias + SiLU -> bf16 ----------------
__global__ __launch_bounds__(256) void conv_silu(
    const u16* __restrict__ xbc, const u16* __restrict__ wtb,
    const float* __restrict__ bias, u16* __restrict__ xc)
{
  const int bid = blockIdx.x;
  const int sb  = (bid & 7)*1152 + (bid >> 3);
  const int idx = sb*256 + threadIdx.x;       // < 8192*288
  const int g   = idx % 288;
  const int row = idx / 288;
  const int l = row & 4095;
  const int c = g*8;
  float a[8];
  float4 b0 = *reinterpret_cast<const float4*>(&bias[c]);
  float4 b1 = *reinterpret_cast<const float4*>(&bias[c+4]);
  a[0]=b0.x; a[1]=b0.y; a[2]=b0.z; a[3]=b0.w;
  a[4]=b1.x; a[5]=b1.y; a[6]=b1.z; a[7]=b1.w;
  #pragma unroll
  for (int t=0;t<7;t++){
    int ls = l + t - 3;
    if (ls >= 0 && ls < 4096){
      bf16x8 v  = *reinterpret_cast<const bf16x8*>(&xbc[(size_t)(row + t - 3)*2304 + c]);
      bf16x8 wv = *reinterpret_cast<const bf16x8*>(&wtb[t*2304 + c]);
      #pragma unroll
      for (int j=0;j<8;j++) a[j] += bf2f((u16)v[j]) * bf2f((u16)wv[j]);
    }
  }
  bf16x8 o;
  #pragma unroll
  for (int j=0;j<8;j++){
    float s = a[j]/(1.f+__expf(-a[j]));
    o[j] = (short)f2bf(s);
  }
  *reinterpret_cast<bf16x8*>(&xc[(size_t)row*2304 + c]) = o;
}

// ================= chunked SSD scan (Q=64), BOTH dirs in one launch =========
// 8192 blocks: dir = blk>>12, slot = blk&4095. dB0 = xbc alias, dB1 = d_out
// scratch (fully rewritten by gemm2 later). LDS-reuse (r13): Gm->Cs, Bwt->Bls.
__global__ __launch_bounds__(256) void ssd_chunk(
    const u16* __restrict__ xc, const u16* __restrict__ dtb,
    const float* __restrict__ dt_bias, const float* __restrict__ A_log,
    u16* __restrict__ ypF, u16* __restrict__ ypB,
    u16* __restrict__ dB0, u16* __restrict__ dB1, float* __restrict__ csum)
{
  const int blk = blockIdx.x;
  const int dir = blk >> 12;
  const int c  = blk & 63;
  const int th = (blk >> 6) & 63;
  const int h  = th & 31;
  const int b  = th >> 5;
  const int tid = threadIdx.x;
  const int wid = tid >> 6;
  const int lane = tid & 63;
  const int lq = lane >> 4, lr = lane & 15;
  u16* yP  = dir ? ypB : ypF;
  u16* dBp = dir ? dB1 : dB0;

  __shared__ __align__(16) u16 Cs[64*64];    // C, then Gm
  __shared__ __align__(16) u16 Bls[64*64];   // B, then Bwt
  __shared__ __align__(16) u16 Xt[64*64];
  __shared__ float cum[64], dtl[64];

  const float Ah = -__expf(A_log[h]);

  for (int e = tid; e < 512; e += 256){
    int i = e >> 3, g = e & 7;
    int l = dir ? (4095 - (c*64+i)) : (c*64+i);
    size_t rb = (size_t)(b*4096 + l)*2304;
    *reinterpret_cast<bf16x8*>(&Bls[i*64+g*8]) =
        *reinterpret_cast<const bf16x8*>(&xc[rb + 2048 + dir*128 + g*8]);
    *reinterpret_cast<bf16x8*>(&Cs[i*64+g*8]) =
        *reinterpret_cast<const bf16x8*>(&xc[rb + 2112 + dir*128 + g*8]);
  }
  for (int e = tid; e < 512; e += 256){
    int i = e & 63, g = e >> 6;
    int l = dir ? (4095 - (c*64+i)) : (c*64+i);
    bf16x8 xv = *reinterpret_cast<const bf16x8*>(&xc[(size_t)(b*4096+l)*2304 + (size_t)h*64 + g*8]);
    #pragma unroll
    for (int j=0;j<8;j++) Xt[(g*8+j)*64 + i] = (u16)xv[j];
  }
  if (tid < 64){
    int i = tid;
    int l = dir ? (4095 - (c*64+i)) : (c*64+i);
    float raw = bf2f(dtb[(size_t)(b*4096+l)*64 + dir*32 + h]) + dt_bias[h];
    float dte = (raw > 20.f) ? raw : log1pf(__expf(raw));
    dtl[i] = dte;
    float s = dte;
    #pragma unroll
    for (int off=1; off<64; off<<=1){
      float o = __shfl_up(s, off, 64);
      if (i >= off) s += o;
    }
    cum[i] = s;
    if (i == 63) csum[blk] = s;
  }
  __syncthreads();

  // G = C @ B^T
  f32x4 g4[4];
  #pragma unroll
  for (int n=0;n<4;n++) g4[n] = (f32x4){0.f,0.f,0.f,0.f};
  #pragma unroll
  for (int kk=0;kk<2;kk++){
    bf16x8 ca = *reinterpret_cast<const bf16x8*>(&Cs[(wid*16+lr)*64 + kk*32 + lq*8]);
    #pragma unroll
    for (int n=0;n<4;n++){
      bf16x8 bb = *reinterpret_cast<const bf16x8*>(&Bls[(n*16+lr)*64 + kk*32 + lq*8]);
      g4[n] = __builtin_amdgcn_mfma_f32_16x16x32_bf16(ca, bb, g4[n], 0,0,0);
    }
  }
  // preload B rows + decay weights for Bwt
  float ctot = cum[63];
  const int j0 = tid & 63, g0 = tid >> 6;
  float wj0 = __expf(Ah*(ctot - cum[j0])) * dtl[j0];
  bf16x8 bv0 = *reinterpret_cast<const bf16x8*>(&Bls[j0*64 + g0*8]);
  const int e1 = tid + 256;
  const int j1 = e1 & 63, g1 = e1 >> 6;
  float wj1 = __expf(Ah*(ctot - cum[j1])) * dtl[j1];
  bf16x8 bv1 = *reinterpret_cast<const bf16x8*>(&Bls[j1*64 + g1*8]);

  __syncthreads();   // all reads of Cs/Bls complete before overwrite

  #pragma unroll
  for (int n=0;n<4;n++){
    #pragma unroll
    for (int r=0;r<4;r++){
      int gi = wid*16 + lq*4 + r;
      int gj = n*16 + lr;
      float wgt = (gj <= gi) ? __expf(Ah*(cum[gi]-cum[gj]))*dtl[gj] : 0.f;
      Cs[gi*64+gj] = f2bf(g4[n][r]*wgt);
    }
  }
  #pragma unroll
  for (int nn=0;nn<8;nn++) Bls[(g0*8+nn)*64 + j0] = f2bf(wj0 * bf2f((u16)bv0[nn]));
  #pragma unroll
  for (int nn=0;nn<8;nn++) Bls[(g1*8+nn)*64 + j1] = f2bf(wj1 * bf2f((u16)bv1[nn]));

  __syncthreads();

  // y_intra = Gm @ X ; dB = X^T @ Bwt^T
  f32x4 yi[4], db4[4];
  #pragma unroll
  for (int n=0;n<4;n++){ yi[n] = (f32x4){0.f,0.f,0.f,0.f}; db4[n] = (f32x4){0.f,0.f,0.f,0.f}; }
  #pragma unroll
  for (int kk=0;kk<2;kk++){
    bf16x8 ga = *reinterpret_cast<const bf16x8*>(&Cs[(wid*16+lr)*64 + kk*32 + lq*8]);
    bf16x8 xa = *reinterpret_cast<const bf16x8*>(&Xt[(wid*16+lr)*64 + kk*32 + lq*8]);
    #pragma unroll
    for (int n=0;n<4;n++){
      bf16x8 xb = *reinterpret_cast<const bf16x8*>(&Xt[(n*16+lr)*64 + kk*32 + lq*8]);
      yi[n] = __builtin_amdgcn_mfma_f32_16x16x32_bf16(ga, xb, yi[n], 0,0,0);
      bf16x8 wb = *reinterpret_cast<const bf16x8*>(&Bls[(n*16+lr)*64 + kk*32 + lq*8]);
      db4[n] = __builtin_amdgcn_mfma_f32_16x16x32_bf16(xa, wb, db4[n], 0,0,0);
    }
  }
  #pragma unroll
  for (int n=0;n<4;n++){
    #pragma unroll
    for (int r=0;r<4;r++){
      int i = wid*16 + lq*4 + r;
      yP[(size_t)(b*4096 + c*64 + i)*2048 + (size_t)h*64 + n*16 + lr] = f2bf(yi[n][r]);
    }
  }
  u16* dst = dBp + (size_t)(blk & 4095)*4096;
  #pragma unroll
  for (int n=0;n<4;n++){
    #pragma unroll
    for (int r=0;r<4;r++){
      int p = wid*16 + lq*4 + r;
      dst[p*64 + n*16 + lr] = f2bf(db4[n][r]);
    }
  }
}

// Pass B1: sequential h-chain over chunks, slot-shift in-place. Both dirs:
// 512 blocks. Software-pipelined: chunk c+1's load issued before chunk c's
// FMAs+store (disjoint addresses; identical FLOP order -> bitwise-same).
__global__ __launch_bounds__(256) void ssd_state(
    u16* __restrict__ dB0, u16* __restrict__ dB1,
    const float* __restrict__ csum, const float* __restrict__ A_log)
{
  const int dir = blockIdx.x >> 8;
  const int r   = blockIdx.x & 255;
  const int q = r & 3;
  const int task = r >> 2;
  const int h = task & 31;
  u16* dBp = dir ? dB1 : dB0;
  const float* cs = csum + dir*4096;
  const float Ah = -__expf(A_log[h]);
  const int p  = q*16 + (threadIdx.x >> 4);
  const int nb = (threadIdx.x & 15) * 4;
  u16* ptr = dBp + ((size_t)task*64)*4096 + p*64 + nb;
  float h0=0.f, h1=0.f, h2=0.f, h3=0.f;
  ushort4 dv = *reinterpret_cast<const ushort4*>(ptr);
  for (int c=0; c<63; ++c){
    float P = __expf(Ah * cs[task*64 + c]);
    ushort4 nxt = dv;
    if (c+1 < 63) nxt = *reinterpret_cast<const ushort4*>(ptr + 4096);
    h0 = P*h0 + bf2f(dv.x);
    h1 = P*h1 + bf2f(dv.y);
    h2 = P*h2 + bf2f(dv.z);
    h3 = P*h3 + bf2f(dv.w);
    *reinterpret_cast<ushort4*>(ptr) = make_ushort4(f2bf(h0),f2bf(h1),f2bf(h2),f2bf(h3));
    dv = nxt;
    ptr += 4096;
  }
}

// Pass B2: y += cd[i] * (C @ h_in^T). Both dirs, c==0 blocks removed:
// 8064 blocks = 2 dirs x 64 (b,h) x 63 chunks.
__global__ __launch_bounds__(256) void ssd_yinter(
    const u16* __restrict__ xc, const u16* __restrict__ dtb,
    const float* __restrict__ dt_bias, const float* __restrict__ A_log,
    const u16* __restrict__ dB0, const u16* __restrict__ dB1,
    u16* __restrict__ ypF, u16* __restrict__ ypB)
{
  const int idx = blockIdx.x;           // < 8064
  const int dir = idx / 4032;
  const int rr  = idx - dir*4032;
  const int c   = 1 + (rr % 63);
  const int th  = rr / 63;
  const int h  = th & 31;
  const int b  = th >> 5;
  const int tid = threadIdx.x;
  const int wid = tid >> 6;
  const int lane = tid & 63;
  const int lq = lane >> 4, lr = lane & 15;
  u16* yP = dir ? ypB : ypF;
  const u16* dBp = dir ? dB1 : dB0;
  const int slot = th*64 + c;

  __shared__ __align__(16) u16 Cs[64*64];
  __shared__ __align__(16) u16 Hs[64*64];
  __shared__ float cum[64];

  const float Ah = -__expf(A_log[h]);

  for (int e = tid; e < 512; e += 256){
    int i = e >> 3, g = e & 7;
    int l = dir ? (4095 - (c*64+i)) : (c*64+i);
    *reinterpret_cast<bf16x8*>(&Cs[i*64+g*8]) =
        *reinterpret_cast<const bf16x8*>(&xc[(size_t)(b*4096+l)*2304 + 2112 + dir*128 + g*8]);
    *reinterpret_cast<bf16x8*>(&Hs[e*8]) =
        *reinterpret_cast<const bf16x8*>(&dBp[(size_t)(slot-1)*4096 + e*8]);
  }
  if (tid < 64){
    int i = tid;
    int l = dir ? (4095 - (c*64+i)) : (c*64+i);
    float raw = bf2f(dtb[(size_t)(b*4096+l)*64 + dir*32 + h]) + dt_bias[h];
    float dte = (raw > 20.f) ? raw : log1pf(__expf(raw));
    float s = dte;
    #pragma unroll
    for (int off=1; off<64; off<<=1){
      float o = __shfl_up(s, off, 64);
      if (i >= off) s += o;
    }
    cum[i] = s;
  }
  __syncthreads();

  f32x4 acc[4];
  #pragma unroll
  for (int n=0;n<4;n++) acc[n] = (f32x4){0.f,0.f,0.f,0.f};
  #pragma unroll
  for (int kk=0;kk<2;kk++){
    bf16x8 ca = *reinterpret_cast<const bf16x8*>(&Cs[(wid*16+lr)*64 + kk*32 + lq*8]);
    #pragma unroll
    for (int n=0;n<4;n++){
      bf16x8 hb = *reinterpret_cast<const bf16x8*>(&Hs[(n*16+lr)*64 + kk*32 + lq*8]);
      acc[n] = __builtin_amdgcn_mfma_f32_16x16x32_bf16(ca, hb, acc[n], 0,0,0);
    }
  }
  #pragma unroll
  for (int n=0;n<4;n++){
    #pragma unroll
    for (int r=0;r<4;r++){
      int i = wid*16 + lq*4 + r;
      float cd = __expf(Ah*cum[i]);
      size_t a = (size_t)(b*4096 + c*64 + i)*2048 + (size_t)h*64 + n*16 + lr;
      yP[a] = f2bf(bf2f(yP[a]) + cd*acc[n][r]);
    }
  }
}

// ---------------- fuse: y-combine(shift/flip) + D*x + RMSNorm + SiLU(z) ------
__global__ __launch_bounds__(256) void fuse_rms(
    const u16* __restrict__ ypF, const u16* __restrict__ ypB,
    const u16* __restrict__ xc, const u16* __restrict__ zbuf,
    u16* __restrict__ un,
    const float* __restrict__ Dscal, const float* __restrict__ D_b,
    const float* __restrict__ rms_w)
{
  const int row = blockIdx.x;
  const int l = row & 4095;
  const int tid = threadIdx.x;
  const int c = tid*8;
  const int hh = tid >> 3;
  float v[8]; float ss = 0.f;
  const bool hasF = (l >= 1);
  const bool hasB = (l <= 4094);
  bf16x8 yf, yb;
  if (hasF) yf = *reinterpret_cast<const bf16x8*>(&ypF[(size_t)(row-1)*2048 + c]);
  if (hasB) yb = *reinterpret_cast<const bf16x8*>(&ypB[(size_t)(row + 4094 - 2*l)*2048 + c]);
  bf16x8 xv = *reinterpret_cast<const bf16x8*>(&xc[(size_t)row*2304 + c]);
  const float dsc = Dscal[(size_t)row*32 + hh] + D_b[hh];
  #pragma unroll
  for (int i=0;i<8;i++){
    float y = hasF ? bf2f((u16)yf[i]) : 0.f;
    if (hasB) y += bf2f((u16)yb[i]);
    y += dsc * bf2f((u16)xv[i]);
    v[i] = y;
    ss += y*y;
  }
  #pragma unroll
  for (int o=1;o<64;o<<=1) ss += __shfl_xor(ss, o, 64);
  __shared__ float sred[4];
  if ((tid & 63) == 0) sred[tid>>6] = ss;
  __syncthreads();
  float rstd = rsqrtf((sred[0]+sred[1]+sred[2]+sred[3]) * (1.f/2048.f) + 1e-5f);
  bf16x8 zv = *reinterpret_cast<const bf16x8*>(&zbuf[(size_t)row*2048 + c]);
  bf16x8 o;
  #pragma unroll
  for (int i=0;i<8;i++){
    float z = bf2f((u16)zv[i]);
    float sz = z / (1.f + __expf(-z));
    o[i] = (short)f2bf(v[i]*rstd*rms_w[c+i]*sz);
  }
  *reinterpret_cast<bf16x8*>(&un[(size_t)row*2048 + c]) = o;
}

extern "C" void kernel_launch(void* const* d_in, const int* in_sizes, int n_in,
                              void* d_out, int out_size, void* d_ws, size_t ws_size,
                              hipStream_t stream)
{
  const float* u       = (const float*)d_in[0];
  const float* w_in    = (const float*)d_in[1];
  const float* conv_w  = (const float*)d_in[2];
  const float* conv_b  = (const float*)d_in[3];
  const float* dt_bias = (const float*)d_in[4];
  const float* A_log   = (const float*)d_in[5];
  const float* D_w     = (const float*)d_in[6];
  const float* D_b     = (const float*)d_in[7];
  const float* rms_w   = (const float*)d_in[8];
  const float* w_out   = (const float*)d_in[9];
  float* out = (float*)d_out;
  (void)in_sizes; (void)n_in; (void)out_size; (void)ws_size;

  char* ws = (char*)d_ws;
  u16*   zbuf = (u16*)(ws);                         // 8192x2048 bf16
  u16*   xbc  = (u16*)(ws + 33554432);              // 8192x2304 bf16 (dead after conv -> dB0 -> un)
  u16*   dtbuf= (u16*)(ws + 71303168);              // 8192x64  bf16
  u16*   xc   = (u16*)(ws + 72351744);              // 8192x2304 bf16
  u16*   ypF  = (u16*)(ws + 110100480);             // 8192x2048 bf16
  u16*   ypB  = (u16*)(ws + 143654912);             // 8192x2048 bf16
  float* Dsc  = (float*)(ws + 177209344);           // 8192x32 f32
  u16*   w2b  = (u16*)(ws + 178257920);             // 1024x2048 bf16
  u16*   dwb  = (u16*)(ws + 182452224);             // 32x2048 bf16
  float* csum = (float*)(ws + 182583296);           // 2 x 4096 f32
  u16*   wtb  = (u16*)(ws + 182616064);             // 7x2304 bf16
  // aliases
  u16*   ub   = ypF;
  u16*   w1b  = ypF + (size_t)8192*1024;
  u16*   dB0  = xbc;                                // dir0 chunk-state buffer
  u16*   dB1  = (u16*)out;                          // dir1: d_out as scratch
                                                    // (exact 33.55MB fit; gemm2
                                                    //  fully rewrites out later)
  u16*   un   = xbc;

  // merged prep: u/w_in/w_out/D_w cvt + conv-weight transpose (one launch)
  prep_all<<<14783,256,0,stream>>>(u, w_in, w_out, D_w, conv_w,
                                   ub, w1b, w2b, dwb, wtb);

  // zxBCdt = u @ in_proj_w^T  (split into zbuf / xbc / dtbuf)
  gemm_p<1,2,128,128,2,2><<<dim3(35,64),256,0,stream>>>(ub,1024, w1b,1024, nullptr,0,
                                                        8192,4416,1024, zbuf, xbc, dtbuf);
  // depthwise conv + silu -> xc
  conv_silu<<<9216,256,0,stream>>>(xbc, wtb, conv_b, xc);
  // Dscal = x_og @ D_w^T  (f32)
  gemm_p<1,0,64,64,2,2><<<dim3(1,128),256,0,stream>>>(xc,2304, dwb,2048, Dsc,32,
                                                      8192,32,2048, nullptr,nullptr,nullptr);
  // chunked SSD scan, BOTH directions per launch
  ssd_chunk <<<8192,256,0,stream>>>(xc, dtbuf, dt_bias, A_log, ypF, ypB, dB0, dB1, csum);
  ssd_state <<<512, 256,0,stream>>>(dB0, dB1, csum, A_log);
  ssd_yinter<<<8064,256,0,stream>>>(xc, dtbuf, dt_bias, A_log, dB0, dB1, ypF, ypB);
  // combine + D path + RMS + gate -> un
  fuse_rms<<<8192,256,0,stream>>>(ypF, ypB, xc, zbuf, un, Dsc, D_b, rms_w);
  // out = un @ outproj_w^T  (f32): overwrites dB1 scratch entirely
  gemm_p<0,0,128,64,2,2><<<dim3(16,64),256,0,stream>>>(un,2048, w2b,2048, out,1024,
                                                       8192,1024,2048, nullptr,nullptr,nullptr);
}

// Round 16
// 369.305 us; speedup vs baseline: 1.0472x; 1.0472x over previous
//
#include <hip/hip_runtime.h>

typedef unsigned short u16;
typedef __attribute__((ext_vector_type(8))) short bf16x8;
typedef __attribute__((ext_vector_type(4))) float f32x4;

__device__ __forceinline__ float bf2f(u16 u){
  union { unsigned int i; float f; } x; x.i = ((unsigned int)u) << 16; return x.f;
}
__device__ __forceinline__ u16 f2bf(float f){
  union { float f; unsigned int i; } x; x.f = f;
  unsigned int r = x.i + 0x7fffu + ((x.i >> 16) & 1u);
  return (u16)(r >> 16);
}

template<int N> __device__ __forceinline__ void waitcnt_vm(){
  if constexpr (N==0)       asm volatile("s_waitcnt vmcnt(0)" ::: "memory");
  else if constexpr (N==2)  asm volatile("s_waitcnt vmcnt(2)" ::: "memory");
  else if constexpr (N==3)  asm volatile("s_waitcnt vmcnt(3)" ::: "memory");
  else if constexpr (N==4)  asm volatile("s_waitcnt vmcnt(4)" ::: "memory");
  else if constexpr (N==6)  asm volatile("s_waitcnt vmcnt(6)" ::: "memory");
  else if constexpr (N==8)  asm volatile("s_waitcnt vmcnt(8)" ::: "memory");
  else if constexpr (N==12) asm volatile("s_waitcnt vmcnt(12)" ::: "memory");
}

// ---------------- merged prep: 4x f32->bf16 cvt + conv weight transpose -----
__device__ __forceinline__ void cvt4(const float* __restrict__ in,
                                     u16* __restrict__ out, int blk){
  int i = blk*256 + threadIdx.x;
  float4 v = reinterpret_cast<const float4*>(in)[i];
  reinterpret_cast<ushort4*>(out)[i] =
      make_ushort4(f2bf(v.x), f2bf(v.y), f2bf(v.z), f2bf(v.w));
}
__global__ __launch_bounds__(256) void prep_all(
    const float* __restrict__ u, const float* __restrict__ w_in,
    const float* __restrict__ w_out, const float* __restrict__ D_w,
    const float* __restrict__ conv_w,
    u16* __restrict__ ub, u16* __restrict__ w1b, u16* __restrict__ w2b,
    u16* __restrict__ dwb, u16* __restrict__ wtb)
{
  const int b = blockIdx.x;
  if      (b < 8192)  cvt4(u,     ub,  b);
  else if (b < 12608) cvt4(w_in,  w1b, b-8192);
  else if (b < 14656) cvt4(w_out, w2b, b-12608);
  else if (b < 14720) cvt4(D_w,   dwb, b-14656);
  else {
    int i = (b-14720)*256 + threadIdx.x;
    if (i < 2304*7){
      int ch = i / 7, t = i % 7;
      wtb[t*2304 + ch] = f2bf(conv_w[i]);
    }
  }
}

// ====== counted-vmcnt pipelined bf16 MFMA GEMM, BK=32, 3 LDS bufs ===========
// SAFE ordering (r8-proven): waitcnt vmcnt(LPS) -> s_barrier -> stage(t+2)
// -> comp(t). Tile ladder measured (r8/r9/r12): 72KB/2-CU=135us,
// 48KB(128x128)/3-CU=110us OPTIMUM, 36KB(128x64)/4-CU=135us. m-fastest XCD
// mapping keeps B-tile hot in per-XCD L2 (r10: FETCH 116->60MB).
// gridDim.y%8==0 required. MODE 0: f32 out. MODE 2: split z/xbc/dt (gemm1).
template<int GUARD, int MODE, int BM, int BN, int NM, int NN>
__global__ __launch_bounds__(256, 3) void gemm_p(
    const u16* __restrict__ A, int lda,
    const u16* __restrict__ Bt, int ldb,
    void* __restrict__ Cp, int ldc,
    int M, int N, int K,
    u16* __restrict__ zb, u16* __restrict__ xb, u16* __restrict__ db_)
{
  constexpr int T   = 64*NM*NN;
  constexpr int MF  = BM/NM/16;
  constexpr int NF  = BN/NN/16;
  constexpr int LPS = (BM+BN)*4/T;       // gload_lds per thread per stage
  __shared__ __align__(16) u16 As[3][BM*32];
  __shared__ __align__(16) u16 Bs[3][BN*32];
  const int tid  = threadIdx.x;
  const int wid  = tid >> 6;
  const int lane = tid & 63;
  // XCD-chunked bijective mapping, m-fastest within XCD (L2 B-tile reuse)
  const int bid   = blockIdx.y * gridDim.x + blockIdx.x;
  const int xcd   = bid & 7;
  const int local = bid >> 3;
  const int mPerX = gridDim.y >> 3;      // m-tiles owned by one XCD
  const int m0 = (xcd*mPerX + (local % mPerX)) * BM;
  const int n0 = (local / mPerX) * BN;
  const int wm = wid / NN;
  const int wn = wid % NN;
  const int lq = lane >> 4, lr = lane & 15;
  // read-side XOR (must match stage()'s source-column XOR)
  const int ce = (lq ^ ((lr&3) ^ ((lr>>2)&3))) * 8;

  f32x4 acc[MF][NF];
  #pragma unroll
  for (int m=0;m<MF;m++)
    #pragma unroll
    for (int n=0;n<NF;n++) acc[m][n] = (f32x4){0.f,0.f,0.f,0.f};

  auto stage = [&](int t){
    const int buf = t % 3;
    const int k0  = t << 5;
    #pragma unroll
    for (int i=0;i<(BM*4)/T;i++){
      int slot = i*T + tid;
      int row = slot >> 2, cg = slot & 3;
      int sc = cg ^ ((row&3) ^ ((row>>2)&3));
      const u16* ga = A + (size_t)(m0 + row)*lda + k0 + sc*8;
      __builtin_amdgcn_global_load_lds(
        (const __attribute__((address_space(1))) void*)ga,
        (__attribute__((address_space(3))) void*)&As[buf][slot*8], 16, 0, 0);
    }
    #pragma unroll
    for (int i=0;i<(BN*4)/T;i++){
      int slot = i*T + tid;
      int row = slot >> 2, cg = slot & 3;
      int gn = n0 + row;
      if (GUARD) gn = (gn < N) ? gn : (N-1);
      int sc = cg ^ ((row&3) ^ ((row>>2)&3));
      const u16* gb = Bt + (size_t)gn*ldb + k0 + sc*8;
      __builtin_amdgcn_global_load_lds(
        (const __attribute__((address_space(1))) void*)gb,
        (__attribute__((address_space(3))) void*)&Bs[buf][slot*8], 16, 0, 0);
    }
  };

  auto comp = [&](int t){
    const int buf = t % 3;
    bf16x8 af[MF], bfr[NF];
    #pragma unroll
    for (int m=0;m<MF;m++){
      int row = wm*(MF*16) + m*16 + lr;
      af[m] = *reinterpret_cast<const bf16x8*>(&As[buf][row*32 + ce]);
    }
    #pragma unroll
    for (int n=0;n<NF;n++){
      int row = wn*(NF*16) + n*16 + lr;
      bfr[n] = *reinterpret_cast<const bf16x8*>(&Bs[buf][row*32 + ce]);
    }
    __builtin_amdgcn_s_setprio(1);
    #pragma unroll
    for (int m=0;m<MF;m++)
      #pragma unroll
      for (int n=0;n<NF;n++)
        acc[m][n] = __builtin_amdgcn_mfma_f32_16x16x32_bf16(af[m], bfr[n], acc[m][n], 0,0,0);
    __builtin_amdgcn_s_setprio(0);
  };

  const int nt = K >> 5;                 // >= 4 for all our shapes
  stage(0); stage(1);
  for (int t=0; t<nt; ++t){
    if (t+1 < nt) waitcnt_vm<LPS>();
    else          waitcnt_vm<0>();
    asm volatile("s_barrier" ::: "memory");
    if (t+2 < nt) stage(t+2);
    comp(t);
  }

  #pragma unroll
  for (int m=0;m<MF;m++){
    int row = m0 + wm*(MF*16) + m*16 + lq*4;
    #pragma unroll
    for (int n=0;n<NF;n++){
      int col = n0 + wn*(NF*16) + n*16 + lr;
      if (!GUARD || col < N){
        #pragma unroll
        for (int j=0;j<4;j++){
          float v = acc[m][n][j];
          size_t r = (size_t)(row+j);
          if (MODE == 0)      ((float*)Cp)[r*ldc + col] = v;
          else if (MODE == 1) ((u16*)Cp)[r*ldc + col] = f2bf(v);
          else {
            u16 bv = f2bf(v);
            if (col < 2048)      zb[r*2048 + col] = bv;
            else if (col < 4352) xb[r*2304 + (col-2048)] = bv;
            else                 db_[r*64 + (col-4352)] = bv;
          }
        }
      }
    }
  }
}

// ---------------- depthwise conv7 (SAME) + bias + SiLU -> bf16 ----------------
__global__ __launch_bounds__(256) void conv_silu(
    const u16* __restrict__ xbc, const u16* __restrict__ wtb,
    const float* __restrict__ bias, u16* __restrict__ xc)
{
  const int bid = blockIdx.x;
  const int sb  = (bid & 7)*1152 + (bid >> 3);
  const int idx = sb*256 + threadIdx.x;       // < 8192*288
  const int g   = idx % 288;
  const int row = idx / 288;
  const int l = row & 4095;
  const int c = g*8;
  float a[8];
  float4 b0 = *reinterpret_cast<const float4*>(&bias[c]);
  float4 b1 = *reinterpret_cast<const float4*>(&bias[c+4]);
  a[0]=b0.x; a[1]=b0.y; a[2]=b0.z; a[3]=b0.w;
  a[4]=b1.x; a[5]=b1.y; a[6]=b1.z; a[7]=b1.w;
  #pragma unroll
  for (int t=0;t<7;t++){
    int ls = l + t - 3;
    if (ls >= 0 && ls < 4096){
      bf16x8 v  = *reinterpret_cast<const bf16x8*>(&xbc[(size_t)(row + t - 3)*2304 + c]);
      bf16x8 wv = *reinterpret_cast<const bf16x8*>(&wtb[t*2304 + c]);
      #pragma unroll
      for (int j=0;j<8;j++) a[j] += bf2f((u16)v[j]) * bf2f((u16)wv[j]);
    }
  }
  bf16x8 o;
  #pragma unroll
  for (int j=0;j<8;j++){
    float s = a[j]/(1.f+__expf(-a[j]));
    o[j] = (short)f2bf(s);
  }
  *reinterpret_cast<bf16x8*>(&xc[(size_t)row*2304 + c]) = o;
}

// ================= chunked SSD scan (Q=64), BOTH dirs in one launch =========
// 8192 blocks: dir = blk>>12, slot = blk&4095. dB0 = xbc alias, dB1 = d_out
// scratch (fully rewritten by gemm2 later). LDS-reuse (r13): Gm->Cs, Bwt->Bls.
__global__ __launch_bounds__(256) void ssd_chunk(
    const u16* __restrict__ xc, const u16* __restrict__ dtb,
    const float* __restrict__ dt_bias, const float* __restrict__ A_log,
    u16* __restrict__ ypF, u16* __restrict__ ypB,
    u16* __restrict__ dB0, u16* __restrict__ dB1, float* __restrict__ csum)
{
  const int blk = blockIdx.x;
  const int dir = blk >> 12;
  const int c  = blk & 63;
  const int th = (blk >> 6) & 63;
  const int h  = th & 31;
  const int b  = th >> 5;
  const int tid = threadIdx.x;
  const int wid = tid >> 6;
  const int lane = tid & 63;
  const int lq = lane >> 4, lr = lane & 15;
  u16* yP  = dir ? ypB : ypF;
  u16* dBp = dir ? dB1 : dB0;

  __shared__ __align__(16) u16 Cs[64*64];    // C, then Gm
  __shared__ __align__(16) u16 Bls[64*64];   // B, then Bwt
  __shared__ __align__(16) u16 Xt[64*64];
  __shared__ float cum[64], dtl[64];

  const float Ah = -__expf(A_log[h]);

  for (int e = tid; e < 512; e += 256){
    int i = e >> 3, g = e & 7;
    int l = dir ? (4095 - (c*64+i)) : (c*64+i);
    size_t rb = (size_t)(b*4096 + l)*2304;
    *reinterpret_cast<bf16x8*>(&Bls[i*64+g*8]) =
        *reinterpret_cast<const bf16x8*>(&xc[rb + 2048 + dir*128 + g*8]);
    *reinterpret_cast<bf16x8*>(&Cs[i*64+g*8]) =
        *reinterpret_cast<const bf16x8*>(&xc[rb + 2112 + dir*128 + g*8]);
  }
  for (int e = tid; e < 512; e += 256){
    int i = e & 63, g = e >> 6;
    int l = dir ? (4095 - (c*64+i)) : (c*64+i);
    bf16x8 xv = *reinterpret_cast<const bf16x8*>(&xc[(size_t)(b*4096+l)*2304 + (size_t)h*64 + g*8]);
    #pragma unroll
    for (int j=0;j<8;j++) Xt[(g*8+j)*64 + i] = (u16)xv[j];
  }
  if (tid < 64){
    int i = tid;
    int l = dir ? (4095 - (c*64+i)) : (c*64+i);
    float raw = bf2f(dtb[(size_t)(b*4096+l)*64 + dir*32 + h]) + dt_bias[h];
    float dte = (raw > 20.f) ? raw : log1pf(__expf(raw));
    dtl[i] = dte;
    float s = dte;
    #pragma unroll
    for (int off=1; off<64; off<<=1){
      float o = __shfl_up(s, off, 64);
      if (i >= off) s += o;
    }
    cum[i] = s;
    if (i == 63) csum[blk] = s;
  }
  __syncthreads();

  // G = C @ B^T
  f32x4 g4[4];
  #pragma unroll
  for (int n=0;n<4;n++) g4[n] = (f32x4){0.f,0.f,0.f,0.f};
  #pragma unroll
  for (int kk=0;kk<2;kk++){
    bf16x8 ca = *reinterpret_cast<const bf16x8*>(&Cs[(wid*16+lr)*64 + kk*32 + lq*8]);
    #pragma unroll
    for (int n=0;n<4;n++){
      bf16x8 bb = *reinterpret_cast<const bf16x8*>(&Bls[(n*16+lr)*64 + kk*32 + lq*8]);
      g4[n] = __builtin_amdgcn_mfma_f32_16x16x32_bf16(ca, bb, g4[n], 0,0,0);
    }
  }
  // preload B rows + decay weights for Bwt
  float ctot = cum[63];
  const int j0 = tid & 63, g0 = tid >> 6;
  float wj0 = __expf(Ah*(ctot - cum[j0])) * dtl[j0];
  bf16x8 bv0 = *reinterpret_cast<const bf16x8*>(&Bls[j0*64 + g0*8]);
  const int e1 = tid + 256;
  const int j1 = e1 & 63, g1 = e1 >> 6;
  float wj1 = __expf(Ah*(ctot - cum[j1])) * dtl[j1];
  bf16x8 bv1 = *reinterpret_cast<const bf16x8*>(&Bls[j1*64 + g1*8]);

  __syncthreads();   // all reads of Cs/Bls complete before overwrite

  #pragma unroll
  for (int n=0;n<4;n++){
    #pragma unroll
    for (int r=0;r<4;r++){
      int gi = wid*16 + lq*4 + r;
      int gj = n*16 + lr;
      float wgt = (gj <= gi) ? __expf(Ah*(cum[gi]-cum[gj]))*dtl[gj] : 0.f;
      Cs[gi*64+gj] = f2bf(g4[n][r]*wgt);
    }
  }
  #pragma unroll
  for (int nn=0;nn<8;nn++) Bls[(g0*8+nn)*64 + j0] = f2bf(wj0 * bf2f((u16)bv0[nn]));
  #pragma unroll
  for (int nn=0;nn<8;nn++) Bls[(g1*8+nn)*64 + j1] = f2bf(wj1 * bf2f((u16)bv1[nn]));

  __syncthreads();

  // y_intra = Gm @ X ; dB = X^T @ Bwt^T
  f32x4 yi[4], db4[4];
  #pragma unroll
  for (int n=0;n<4;n++){ yi[n] = (f32x4){0.f,0.f,0.f,0.f}; db4[n] = (f32x4){0.f,0.f,0.f,0.f}; }
  #pragma unroll
  for (int kk=0;kk<2;kk++){
    bf16x8 ga = *reinterpret_cast<const bf16x8*>(&Cs[(wid*16+lr)*64 + kk*32 + lq*8]);
    bf16x8 xa = *reinterpret_cast<const bf16x8*>(&Xt[(wid*16+lr)*64 + kk*32 + lq*8]);
    #pragma unroll
    for (int n=0;n<4;n++){
      bf16x8 xb = *reinterpret_cast<const bf16x8*>(&Xt[(n*16+lr)*64 + kk*32 + lq*8]);
      yi[n] = __builtin_amdgcn_mfma_f32_16x16x32_bf16(ga, xb, yi[n], 0,0,0);
      bf16x8 wb = *reinterpret_cast<const bf16x8*>(&Bls[(n*16+lr)*64 + kk*32 + lq*8]);
      db4[n] = __builtin_amdgcn_mfma_f32_16x16x32_bf16(xa, wb, db4[n], 0,0,0);
    }
  }
  #pragma unroll
  for (int n=0;n<4;n++){
    #pragma unroll
    for (int r=0;r<4;r++){
      int i = wid*16 + lq*4 + r;
      yP[(size_t)(b*4096 + c*64 + i)*2048 + (size_t)h*64 + n*16 + lr] = f2bf(yi[n][r]);
    }
  }
  u16* dst = dBp + (size_t)(blk & 4095)*4096;
  #pragma unroll
  for (int n=0;n<4;n++){
    #pragma unroll
    for (int r=0;r<4;r++){
      int p = wid*16 + lq*4 + r;
      dst[p*64 + n*16 + lr] = f2bf(db4[n][r]);
    }
  }
}

// Pass B1: sequential h-chain over chunks, slot-shift in-place. Both dirs:
// 512 blocks (dir = blk>>8) -> 2 blocks/CU.
__global__ __launch_bounds__(256) void ssd_state(
    u16* __restrict__ dB0, u16* __restrict__ dB1,
    const float* __restrict__ csum, const float* __restrict__ A_log)
{
  const int dir = blockIdx.x >> 8;
  const int r   = blockIdx.x & 255;
  const int q = r & 3;
  const int task = r >> 2;
  const int h = task & 31;
  u16* dBp = dir ? dB1 : dB0;
  const float* cs = csum + dir*4096;
  const float Ah = -__expf(A_log[h]);
  const int p  = q*16 + (threadIdx.x >> 4);
  const int nb = (threadIdx.x & 15) * 4;
  float h0=0.f, h1=0.f, h2=0.f, h3=0.f;
  for (int c=0; c<63; ++c){
    float P = __expf(Ah * cs[task*64 + c]);
    u16* ptr = dBp + ((size_t)(task*64 + c))*4096 + p*64 + nb;
    ushort4 dv = *reinterpret_cast<const ushort4*>(ptr);
    h0 = P*h0 + bf2f(dv.x);
    h1 = P*h1 + bf2f(dv.y);
    h2 = P*h2 + bf2f(dv.z);
    h3 = P*h3 + bf2f(dv.w);
    *reinterpret_cast<ushort4*>(ptr) = make_ushort4(f2bf(h0),f2bf(h1),f2bf(h2),f2bf(h3));
  }
}

// Pass B2: y += cd[i] * (C @ h_in^T). Both dirs: 8192 blocks; chunk 0 skipped.
__global__ __launch_bounds__(256) void ssd_yinter(
    const u16* __restrict__ xc, const u16* __restrict__ dtb,
    const float* __restrict__ dt_bias, const float* __restrict__ A_log,
    const u16* __restrict__ dB0, const u16* __restrict__ dB1,
    u16* __restrict__ ypF, u16* __restrict__ ypB)
{
  const int blk = blockIdx.x;
  const int c  = blk & 63;
  if (c == 0) return;
  const int dir = blk >> 12;
  const int th = (blk >> 6) & 63;
  const int h  = th & 31;
  const int b  = th >> 5;
  const int tid = threadIdx.x;
  const int wid = tid >> 6;
  const int lane = tid & 63;
  const int lq = lane >> 4, lr = lane & 15;
  u16* yP = dir ? ypB : ypF;
  const u16* dBp = dir ? dB1 : dB0;

  __shared__ __align__(16) u16 Cs[64*64];
  __shared__ __align__(16) u16 Hs[64*64];
  __shared__ float cum[64];

  const float Ah = -__expf(A_log[h]);

  for (int e = tid; e < 512; e += 256){
    int i = e >> 3, g = e & 7;
    int l = dir ? (4095 - (c*64+i)) : (c*64+i);
    *reinterpret_cast<bf16x8*>(&Cs[i*64+g*8]) =
        *reinterpret_cast<const bf16x8*>(&xc[(size_t)(b*4096+l)*2304 + 2112 + dir*128 + g*8]);
    *reinterpret_cast<bf16x8*>(&Hs[e*8]) =
        *reinterpret_cast<const bf16x8*>(&dBp[(size_t)((blk & 4095)-1)*4096 + e*8]);
  }
  if (tid < 64){
    int i = tid;
    int l = dir ? (4095 - (c*64+i)) : (c*64+i);
    float raw = bf2f(dtb[(size_t)(b*4096+l)*64 + dir*32 + h]) + dt_bias[h];
    float dte = (raw > 20.f) ? raw : log1pf(__expf(raw));
    float s = dte;
    #pragma unroll
    for (int off=1; off<64; off<<=1){
      float o = __shfl_up(s, off, 64);
      if (i >= off) s += o;
    }
    cum[i] = s;
  }
  __syncthreads();

  f32x4 acc[4];
  #pragma unroll
  for (int n=0;n<4;n++) acc[n] = (f32x4){0.f,0.f,0.f,0.f};
  #pragma unroll
  for (int kk=0;kk<2;kk++){
    bf16x8 ca = *reinterpret_cast<const bf16x8*>(&Cs[(wid*16+lr)*64 + kk*32 + lq*8]);
    #pragma unroll
    for (int n=0;n<4;n++){
      bf16x8 hb = *reinterpret_cast<const bf16x8*>(&Hs[(n*16+lr)*64 + kk*32 + lq*8]);
      acc[n] = __builtin_amdgcn_mfma_f32_16x16x32_bf16(ca, hb, acc[n], 0,0,0);
    }
  }
  #pragma unroll
  for (int n=0;n<4;n++){
    #pragma unroll
    for (int r=0;r<4;r++){
      int i = wid*16 + lq*4 + r;
      float cd = __expf(Ah*cum[i]);
      size_t a = (size_t)(b*4096 + c*64 + i)*2048 + (size_t)h*64 + n*16 + lr;
      yP[a] = f2bf(bf2f(yP[a]) + cd*acc[n][r]);
    }
  }
}

// ---------------- fuse: y-combine(shift/flip) + D*x + RMSNorm + SiLU(z) ------
__global__ __launch_bounds__(256) void fuse_rms(
    const u16* __restrict__ ypF, const u16* __restrict__ ypB,
    const u16* __restrict__ xc, const u16* __restrict__ zbuf,
    u16* __restrict__ un,
    const float* __restrict__ Dscal, const float* __restrict__ D_b,
    const float* __restrict__ rms_w)
{
  const int row = blockIdx.x;
  const int l = row & 4095;
  const int tid = threadIdx.x;
  const int c = tid*8;
  const int hh = tid >> 3;
  float v[8]; float ss = 0.f;
  const bool hasF = (l >= 1);
  const bool hasB = (l <= 4094);
  bf16x8 yf, yb;
  if (hasF) yf = *reinterpret_cast<const bf16x8*>(&ypF[(size_t)(row-1)*2048 + c]);
  if (hasB) yb = *reinterpret_cast<const bf16x8*>(&ypB[(size_t)(row + 4094 - 2*l)*2048 + c]);
  bf16x8 xv = *reinterpret_cast<const bf16x8*>(&xc[(size_t)row*2304 + c]);
  const float dsc = Dscal[(size_t)row*32 + hh] + D_b[hh];
  #pragma unroll
  for (int i=0;i<8;i++){
    float y = hasF ? bf2f((u16)yf[i]) : 0.f;
    if (hasB) y += bf2f((u16)yb[i]);
    y += dsc * bf2f((u16)xv[i]);
    v[i] = y;
    ss += y*y;
  }
  #pragma unroll
  for (int o=1;o<64;o<<=1) ss += __shfl_xor(ss, o, 64);
  __shared__ float sred[4];
  if ((tid & 63) == 0) sred[tid>>6] = ss;
  __syncthreads();
  float rstd = rsqrtf((sred[0]+sred[1]+sred[2]+sred[3]) * (1.f/2048.f) + 1e-5f);
  bf16x8 zv = *reinterpret_cast<const bf16x8*>(&zbuf[(size_t)row*2048 + c]);
  bf16x8 o;
  #pragma unroll
  for (int i=0;i<8;i++){
    float z = bf2f((u16)zv[i]);
    float sz = z / (1.f + __expf(-z));
    o[i] = (short)f2bf(v[i]*rstd*rms_w[c+i]*sz);
  }
  *reinterpret_cast<bf16x8*>(&un[(size_t)row*2048 + c]) = o;
}

extern "C" void kernel_launch(void* const* d_in, const int* in_sizes, int n_in,
                              void* d_out, int out_size, void* d_ws, size_t ws_size,
                              hipStream_t stream)
{
  const float* u       = (const float*)d_in[0];
  const float* w_in    = (const float*)d_in[1];
  const float* conv_w  = (const float*)d_in[2];
  const float* conv_b  = (const float*)d_in[3];
  const float* dt_bias = (const float*)d_in[4];
  const float* A_log   = (const float*)d_in[5];
  const float* D_w     = (const float*)d_in[6];
  const float* D_b     = (const float*)d_in[7];
  const float* rms_w   = (const float*)d_in[8];
  const float* w_out   = (const float*)d_in[9];
  float* out = (float*)d_out;
  (void)in_sizes; (void)n_in; (void)out_size; (void)ws_size;

  char* ws = (char*)d_ws;
  u16*   zbuf = (u16*)(ws);                         // 8192x2048 bf16
  u16*   xbc  = (u16*)(ws + 33554432);              // 8192x2304 bf16 (dead after conv -> dB0 -> un)
  u16*   dtbuf= (u16*)(ws + 71303168);              // 8192x64  bf16
  u16*   xc   = (u16*)(ws + 72351744);              // 8192x2304 bf16
  u16*   ypF  = (u16*)(ws + 110100480);             // 8192x2048 bf16
  u16*   ypB  = (u16*)(ws + 143654912);             // 8192x2048 bf16
  float* Dsc  = (float*)(ws + 177209344);           // 8192x32 f32
  u16*   w2b  = (u16*)(ws + 178257920);             // 1024x2048 bf16
  u16*   dwb  = (u16*)(ws + 182452224);             // 32x2048 bf16
  float* csum = (float*)(ws + 182583296);           // 2 x 4096 f32
  u16*   wtb  = (u16*)(ws + 182616064);             // 7x2304 bf16
  // aliases
  u16*   ub   = ypF;
  u16*   w1b  = ypF + (size_t)8192*1024;
  u16*   dB0  = xbc;                                // dir0 chunk-state buffer
  u16*   dB1  = (u16*)out;                          // dir1: d_out as scratch
                                                    // (exact 33.55MB fit; gemm2
                                                    //  fully rewrites out later)
  u16*   un   = xbc;

  // merged prep: u/w_in/w_out/D_w cvt + conv-weight transpose (one launch)
  prep_all<<<14783,256,0,stream>>>(u, w_in, w_out, D_w, conv_w,
                                   ub, w1b, w2b, dwb, wtb);

  // zxBCdt = u @ in_proj_w^T  (split into zbuf / xbc / dtbuf)
  gemm_p<1,2,128,128,2,2><<<dim3(35,64),256,0,stream>>>(ub,1024, w1b,1024, nullptr,0,
                                                        8192,4416,1024, zbuf, xbc, dtbuf);
  // depthwise conv + silu -> xc
  conv_silu<<<9216,256,0,stream>>>(xbc, wtb, conv_b, xc);
  // Dscal = x_og @ D_w^T  (f32)
  gemm_p<1,0,64,64,2,2><<<dim3(1,128),256,0,stream>>>(xc,2304, dwb,2048, Dsc,32,
                                                      8192,32,2048, nullptr,nullptr,nullptr);
  // chunked SSD scan, BOTH directions per launch
  ssd_chunk <<<8192,256,0,stream>>>(xc, dtbuf, dt_bias, A_log, ypF, ypB, dB0, dB1, csum);
  ssd_state <<<512, 256,0,stream>>>(dB0, dB1, csum, A_log);
  ssd_yinter<<<8192,256,0,stream>>>(xc, dtbuf, dt_bias, A_log, dB0, dB1, ypF, ypB);
  // combine + D path + RMS + gate -> un
  fuse_rms<<<8192,256,0,stream>>>(ypF, ypB, xc, zbuf, un, Dsc, D_b, rms_w);
  // out = un @ outproj_w^T  (f32): overwrites dB1 scratch entirely
  gemm_p<0,0,128,64,2,2><<<dim3(16,64),256,0,stream>>>(un,2048, w2b,2048, out,1024,
                                                       8192,1024,2048, nullptr,nullptr,nullptr);
}